// Round 7
// baseline (186.886 us; speedup 1.0000x reference)
//
#include <hip/hip_runtime.h>
#include <math.h>

#define NR 65536
#define NS 2097152

typedef __attribute__((ext_vector_type(4))) float f32x4;
typedef __attribute__((ext_vector_type(8))) short short8;

#define RSTRIDE 52          // dwords per sample row (48 + 4 pad; 16B-aligned)
#define GSTRIDE (16 * 52 + 4)  // 836 dwords per 16-sample group (bank-staggers groups)

// ---------------- workspace layout ----------------
// [0, NS*8)                : uint2 rgba (bf16 r,g | b,alpha) per sample
// [NS*8, +NR*4)            : int start[NR]
// [+NR*4, +NR*4)           : int end[NR]
// [NS*8+NR*8, +40KB)       : uint4 wfrag[40*64]  (A-fragments, bf16, W^T)

// Native bf16 conversion (RNE fptrunc) — compiler lowers to HW cvt.
__device__ __forceinline__ uint packbf(float a, float b) {
    __bf16 lo = (__bf16)a, hi = (__bf16)b;
    ushort ul = __builtin_bit_cast(ushort, lo);
    ushort uh = __builtin_bit_cast(ushort, hi);
    return (uint)ul | ((uint)uh << 16);
}
__device__ __forceinline__ float bflo(uint u) { return __builtin_bit_cast(float, u << 16); }

__global__ void init_bounds(int* __restrict__ start, int* __restrict__ end) {
    int r = blockIdx.x * blockDim.x + threadIdx.x;
    if (r < NR) { start[r] = 0; end[r] = 0; }
}

__global__ void find_bounds(const int* __restrict__ ridx,
                            int* __restrict__ start, int* __restrict__ end) {
    int i = blockIdx.x * blockDim.x + threadIdx.x;
    if (i >= NS) return;
    int r = ridx[i];
    if (i == 0 || ridx[i - 1] != r) start[r] = i;
    if (i == NS - 1 || ridx[i + 1] != r) end[r] = i + 1;
}

// A-fragments = W^T: lane holds A[m = 16ft + (l&15)][k = 32ks + (l>>4)*8 + e]
//             = W[k][16ft + (l&15)].
// Order: L1 0-7 (f = ks*4+ft), L2 8-15, Wf 16-23, Wr1 24-35, Wd 36-37, Wr2 38-39.
__global__ void build_frags(const float* __restrict__ W1, const float* __restrict__ W2,
                            const float* __restrict__ Wf, const float* __restrict__ Wr1,
                            const float* __restrict__ Wd, const float* __restrict__ Wr2,
                            uint4* __restrict__ wfrag) {
    int t = blockIdx.x * blockDim.x + threadIdx.x;
    if (t >= 40 * 64) return;
    int f = t >> 6, lane = t & 63;
    int c = lane & 15;
    uint q[4];
    if (f < 36) {
        const float* W; int kmax, fl;
        if (f < 8)       { W = W1;  kmax = 63; fl = f; }
        else if (f < 16) { W = W2;  kmax = 64; fl = f - 8; }
        else if (f < 24) { W = Wf;  kmax = 64; fl = f - 16; }
        else             { W = Wr1; kmax = 91; fl = f - 24; }
        int ks = fl >> 2, ft = fl & 3;
        int n = ft * 16 + c;
        int kb = ks * 32 + ((lane >> 4) * 8);
        #pragma unroll
        for (int j = 0; j < 4; ++j) {
            int k0 = kb + 2 * j, k1 = k0 + 1;
            float v0 = (k0 < kmax) ? W[k0 * 64 + n] : 0.0f;
            float v1 = (k1 < kmax) ? W[k1 * 64 + n] : 0.0f;
            q[j] = packbf(v0, v1);
        }
    } else if (f < 38) {          // sigma tile: A[m][k] = (m==0) ? Wd[k] : 0
        int kb = (f - 36) * 32 + ((lane >> 4) * 8);
        #pragma unroll
        for (int j = 0; j < 4; ++j) {
            float v0 = (c == 0) ? Wd[kb + 2 * j] : 0.0f;
            float v1 = (c == 0) ? Wd[kb + 2 * j + 1] : 0.0f;
            q[j] = packbf(v0, v1);
        }
    } else {                      // rgb tile: A[m][k] = (m<3) ? Wr2[k*3+m] : 0
        int kb = (f - 38) * 32 + ((lane >> 4) * 8);
        #pragma unroll
        for (int j = 0; j < 4; ++j) {
            float v0 = (c < 3) ? Wr2[(kb + 2 * j) * 3 + c] : 0.0f;
            float v1 = (c < 3) ? Wr2[(kb + 2 * j + 1) * 3 + c] : 0.0f;
            q[j] = packbf(v0, v1);
        }
    }
    wfrag[(size_t)f * 64 + lane] = make_uint4(q[0], q[1], q[2], q[3]);
}

// LDS layout (sample-major, chunk-XOR swizzled):
//   group st base = (w*4+st)*GSTRIDE; sample row = + s*RSTRIDE (52 dwords).
//   Logical dword c (= bf16 feature pair c) of row s stored at physical
//   dword (c & ~15-block-safe): chunk ch = c>>2 stored at ch ^ (s&3)
//   (XOR within 4-chunk blocks {0-3},{4-7},{8-11} — preserves b128 alignment).
//   Logical dwords 0..31 = activations (64 feats), 32..47 = dir-enc,
//   dword 48 (unswizzled) = dtv.
//   All accesses fold to per-thread base regs + compile-time byte offsets.

template <int KS, bool RELU, bool SIGMA>
__device__ __forceinline__ void dense_layer(uint* S, const uint4* __restrict__ wfrag,
                                            int fb, const float* __restrict__ bias,
                                            float bd0, uint rbase, uint wbA, uint wbB,
                                            int lane, float* sigout) {
    const int g = lane >> 4;
    uint4 wf[KS * 4];
    #pragma unroll
    for (int i = 0; i < KS * 4; ++i) wf[i] = wfrag[(size_t)(fb + i) * 64 + lane];
    uint4 wsg[2];
    if constexpr (SIGMA) {
        wsg[0] = wfrag[36 * 64 + lane];
        wsg[1] = wfrag[37 * 64 + lane];
    }
    float4 bfr[4];
    #pragma unroll
    for (int ft = 0; ft < 4; ++ft)
        bfr[ft] = *(const float4*)(bias + 16 * ft + 4 * g);

    #pragma unroll
    for (int st = 0; st < 4; ++st) {
        const uint stoff = (uint)st * (uint)GSTRIDE;
        uint4 B[KS];
        #pragma unroll
        for (int ks = 0; ks < KS; ++ks)
            B[ks] = *(const uint4*)&S[rbase + stoff + 16u * (uint)ks];  // ds_read_b128
        f32x4 acc[4];
        #pragma unroll
        for (int ft = 0; ft < 4; ++ft)
            acc[ft] = (f32x4){bfr[ft].x, bfr[ft].y, bfr[ft].z, bfr[ft].w};
        f32x4 sacc;
        if constexpr (SIGMA) sacc = (f32x4){(g == 0) ? bd0 : 0.0f, 0.0f, 0.0f, 0.0f};
        #pragma unroll
        for (int ks = 0; ks < KS; ++ks) {
            short8 bv = __builtin_bit_cast(short8, B[ks]);
            #pragma unroll
            for (int ft = 0; ft < 4; ++ft)
                acc[ft] = __builtin_amdgcn_mfma_f32_16x16x32_bf16(
                    __builtin_bit_cast(short8, wf[ks * 4 + ft]), bv, acc[ft], 0, 0, 0);
            if constexpr (SIGMA)
                sacc = __builtin_amdgcn_mfma_f32_16x16x32_bf16(
                    __builtin_bit_cast(short8, wsg[ks]), bv, sacc, 0, 0, 0);
        }
        // D layout: col = lane&15 = sample, row = 4g + reg = out-feature.
        // Features 16ft+4g..+3 = logical dwords 8ft+2g, 8ft+2g+1 -> one b64.
        #pragma unroll
        for (int ft = 0; ft < 4; ++ft) {
            float a0 = acc[ft][0], a1 = acc[ft][1], a2 = acc[ft][2], a3 = acc[ft][3];
            if constexpr (RELU) {
                a0 = fmaxf(a0, 0.0f); a1 = fmaxf(a1, 0.0f);
                a2 = fmaxf(a2, 0.0f); a3 = fmaxf(a3, 0.0f);
            }
            uint2 v = make_uint2(packbf(a0, a1), packbf(a2, a3));
            uint base = (ft & 1) ? wbB : wbA;
            *(uint2*)&S[base + stoff + 16u * (uint)(ft >> 1)] = v;      // ds_write_b64
        }
        if constexpr (SIGMA) sigout[st] = sacc[0];
    }
}

__global__ __launch_bounds__(256, 3) void fused_mlp(
    const float* __restrict__ rays_o, const float* __restrict__ viewdirs,
    const float* __restrict__ t_starts, const float* __restrict__ t_ends,
    const float* __restrict__ b1, const float* __restrict__ b2,
    const float* __restrict__ bd, const float* __restrict__ bf_,
    const float* __restrict__ br1, const float* __restrict__ br2,
    const int* __restrict__ ridx, const uint4* __restrict__ wfrag,
    uint2* __restrict__ rgba)
{
    __shared__ uint S[16 * GSTRIDE];   // 13376 dwords = 53504 B -> 3 blocks/CU

    const int tid = threadIdx.x;
    const int w = tid >> 6, lane = tid & 63;
    const int g = lane >> 4, s = lane & 15;
    const uint sw = 4u * (uint)(s & 3);
    const uint wgb = (uint)(w * 4) * (uint)GSTRIDE;
    const uint rowcol = wgb + (uint)s * (uint)RSTRIDE;          // group 0 of wave, row s
    const int si = blockIdx.x * 256 + tid;

    int rr = ridx[si];
    float ts = t_starts[si], te = t_ends[si];
    float tm = 0.5f * (ts + te), dtv = te - ts;
    float dx = viewdirs[3 * rr + 0], dy = viewdirs[3 * rr + 1], dz = viewdirs[3 * rr + 2];
    float px = rays_o[3 * rr + 0] + dx * tm;
    float py = rays_o[3 * rr + 1] + dy * tm;
    float pz = rays_o[3 * rr + 2] + dz * tm;

    // Per-thread base registers (all later accesses are base + imm offset):
    const uint ownrow = wgb + (uint)g * (uint)GSTRIDE + (uint)s * (uint)RSTRIDE;
    uint pw[4];
    #pragma unroll
    for (int j = 0; j < 4; ++j) pw[j] = ownrow + ((4u * (uint)j) ^ sw);
    const uint rbase = rowcol + ((4u * (uint)g) ^ sw);
    const uint g1 = (uint)(g >> 1), ge2 = 2u * (uint)(g & 1);
    const uint wbA = rowcol + ((4u * g1) ^ sw) + ge2;
    const uint wbB = rowcol + ((8u + 4u * g1) ^ sw) + ge2;

    // ---- posenc(pts,10) via double-angle recurrence -> logical dwords 0..31 ----
    {
        float enc[64];
        enc[0] = px; enc[1] = py; enc[2] = pz;
        float sx = __sinf(px), cx = __cosf(px);
        float sy = __sinf(py), cy = __cosf(py);
        float sz = __sinf(pz), cz = __cosf(pz);
        #pragma unroll
        for (int l = 0; l < 10; ++l) {
            enc[3 + 6 * l + 0] = sx; enc[3 + 6 * l + 1] = sy; enc[3 + 6 * l + 2] = sz;
            enc[3 + 6 * l + 3] = cx; enc[3 + 6 * l + 4] = cy; enc[3 + 6 * l + 5] = cz;
            float nsx = 2.0f * sx * cx, nsy = 2.0f * sy * cy, nsz = 2.0f * sz * cz;
            cx = fmaf(-2.0f * sx, sx, 1.0f);
            cy = fmaf(-2.0f * sy, sy, 1.0f);
            cz = fmaf(-2.0f * sz, sz, 1.0f);
            sx = nsx; sy = nsy; sz = nsz;
        }
        enc[63] = 0.0f;
        #pragma unroll
        for (int ch = 0; ch < 8; ++ch) {
            uint4 q = make_uint4(packbf(enc[8 * ch + 0], enc[8 * ch + 1]),
                                 packbf(enc[8 * ch + 2], enc[8 * ch + 3]),
                                 packbf(enc[8 * ch + 4], enc[8 * ch + 5]),
                                 packbf(enc[8 * ch + 6], enc[8 * ch + 7]));
            *(uint4*)&S[pw[ch & 3] + 16u * (uint)(ch >> 2)] = q;        // ds_write_b128
        }
    }
    // ---- posenc(d,4) -> logical dwords 32..47 (chunks 8..11) ----
    {
        float de[32];
        de[0] = dx; de[1] = dy; de[2] = dz;
        float sx = __sinf(dx), cx = __cosf(dx);
        float sy = __sinf(dy), cy = __cosf(dy);
        float sz = __sinf(dz), cz = __cosf(dz);
        #pragma unroll
        for (int l = 0; l < 4; ++l) {
            de[3 + 6 * l + 0] = sx; de[3 + 6 * l + 1] = sy; de[3 + 6 * l + 2] = sz;
            de[3 + 6 * l + 3] = cx; de[3 + 6 * l + 4] = cy; de[3 + 6 * l + 5] = cz;
            float nsx = 2.0f * sx * cx, nsy = 2.0f * sy * cy, nsz = 2.0f * sz * cz;
            cx = fmaf(-2.0f * sx, sx, 1.0f);
            cy = fmaf(-2.0f * sy, sy, 1.0f);
            cz = fmaf(-2.0f * sz, sz, 1.0f);
            sx = nsx; sy = nsy; sz = nsz;
        }
        #pragma unroll
        for (int k = 27; k < 32; ++k) de[k] = 0.0f;
        #pragma unroll
        for (int c = 0; c < 4; ++c) {
            int ch = 8 + c;
            uint4 q = make_uint4(packbf(de[8 * c + 0], de[8 * c + 1]),
                                 packbf(de[8 * c + 2], de[8 * c + 3]),
                                 packbf(de[8 * c + 4], de[8 * c + 5]),
                                 packbf(de[8 * c + 6], de[8 * c + 7]));
            *(uint4*)&S[pw[ch & 3] + 16u * (uint)(ch >> 2)] = q;
        }
    }
    S[ownrow + 48] = __builtin_bit_cast(uint, dtv);                     // dtv in row pad

    float sig4[4];
    float bd0 = bd[0];

    dense_layer<2, true,  false>(S, wfrag,  0, b1,  0.0f, rbase, wbA, wbB, lane, sig4);
    dense_layer<2, true,  false>(S, wfrag,  8, b2,  0.0f, rbase, wbA, wbB, lane, sig4);
    dense_layer<2, false, true >(S, wfrag, 16, bf_, bd0,  rbase, wbA, wbB, lane, sig4);
    dense_layer<3, true,  false>(S, wfrag, 24, br1, 0.0f, rbase, wbA, wbB, lane, sig4);

    // ---- rgb tile + epilogue ----
    {
        uint4 wr0 = wfrag[38 * 64 + lane], wr1f = wfrag[39 * 64 + lane];
        float c0 = br2[0], c1 = br2[1], c2 = br2[2];
        #pragma unroll
        for (int st = 0; st < 4; ++st) {
            const uint stoff = (uint)st * (uint)GSTRIDE;
            uint4 B0 = *(const uint4*)&S[rbase + stoff];           // feat chunks 0..3
            uint4 B1 = *(const uint4*)&S[rbase + stoff + 16u];     // feat chunks 4..7
            f32x4 acc = (g == 0) ? (f32x4){c0, c1, c2, 0.0f}
                                 : (f32x4){0.0f, 0.0f, 0.0f, 0.0f};
            acc = __builtin_amdgcn_mfma_f32_16x16x32_bf16(
                __builtin_bit_cast(short8, wr0), __builtin_bit_cast(short8, B0), acc, 0, 0, 0);
            acc = __builtin_amdgcn_mfma_f32_16x16x32_bf16(
                __builtin_bit_cast(short8, wr1f), __builtin_bit_cast(short8, B1), acc, 0, 0, 0);
            if (lane < 16) {
                float sg = fmaxf(sig4[st], 0.0f);
                float dte = __builtin_bit_cast(float,
                    S[wgb + stoff + (uint)lane * (uint)RSTRIDE + 48u]);
                float alpha = 1.0f - __expf(-sg * dte);
                float r0 = 1.0f / (1.0f + __expf(-acc[0]));
                float r1 = 1.0f / (1.0f + __expf(-acc[1]));
                float r2 = 1.0f / (1.0f + __expf(-acc[2]));
                uint2 o;
                o.x = packbf(r0, r1);
                o.y = packbf(r2, alpha);
                rgba[blockIdx.x * 256 + w * 64 + st * 16 + lane] = o;
            }
        }
    }
}

__global__ void render_kernel(const uint2* __restrict__ rgba,
                              const float* __restrict__ t_starts,
                              const float* __restrict__ t_ends,
                              const int* __restrict__ start,
                              const int* __restrict__ end,
                              float* __restrict__ out)
{
    int r = blockIdx.x * blockDim.x + threadIdx.x;
    if (r >= NR) return;
    int sb = start[r], e = end[r];
    float T = 1.0f, c0 = 0.0f, c1 = 0.0f, c2 = 0.0f, op = 0.0f, dp = 0.0f;
    for (int i = sb; i < e; ++i) {
        uint2 q = rgba[i];
        float vr = bflo(q.x & 0xffffu), vg = bflo(q.x >> 16);
        float vb = bflo(q.y & 0xffffu), va = bflo(q.y >> 16);
        float wgt = T * va;
        float tmid = 0.5f * (t_starts[i] + t_ends[i]);
        c0 += wgt * vr; c1 += wgt * vg; c2 += wgt * vb;
        op += wgt; dp += wgt * tmid;
        T *= (1.0f - va);
    }
    float bg = 1.0f - op;
    c0 += bg; c1 += bg; c2 += bg;
    out[3 * r + 0] = c0;
    out[3 * r + 1] = c1;
    out[3 * r + 2] = c2;
    out[3 * NR + r] = op;
    out[4 * NR + r] = dp;
}

extern "C" void kernel_launch(void* const* d_in, const int* in_sizes, int n_in,
                              void* d_out, int out_size, void* d_ws, size_t ws_size,
                              hipStream_t stream) {
    const float* rays_o   = (const float*)d_in[0];
    const float* viewdirs = (const float*)d_in[1];
    const float* t_starts = (const float*)d_in[2];
    const float* t_ends   = (const float*)d_in[3];
    const float* W1  = (const float*)d_in[4];
    const float* b1  = (const float*)d_in[5];
    const float* W2  = (const float*)d_in[6];
    const float* b2  = (const float*)d_in[7];
    const float* Wd  = (const float*)d_in[8];
    const float* bd  = (const float*)d_in[9];
    const float* Wf  = (const float*)d_in[10];
    const float* bf_ = (const float*)d_in[11];
    const float* Wr1 = (const float*)d_in[12];
    const float* br1 = (const float*)d_in[13];
    const float* Wr2 = (const float*)d_in[14];
    const float* br2 = (const float*)d_in[15];
    const int* ridx  = (const int*)d_in[16];
    float* out = (float*)d_out;

    char* ws = (char*)d_ws;
    uint2* rgba = (uint2*)ws;
    int* start = (int*)(ws + (size_t)NS * 8);
    int* end   = start + NR;
    uint4* wfrag = (uint4*)(ws + (size_t)NS * 8 + (size_t)NR * 8);

    build_frags<<<10, 256, 0, stream>>>(W1, W2, Wf, Wr1, Wd, Wr2, wfrag);
    init_bounds<<<NR / 256, 256, 0, stream>>>(start, end);
    find_bounds<<<NS / 256, 256, 0, stream>>>(ridx, start, end);
    fused_mlp<<<NS / 256, 256, 0, stream>>>(
        rays_o, viewdirs, t_starts, t_ends,
        b1, b2, bd, bf_, br1, br2, ridx, wfrag, rgba);
    render_kernel<<<NR / 256, 256, 0, stream>>>(rgba, t_starts, t_ends, start, end, out);
}

// Round 8
// 167.022 us; speedup vs baseline: 1.1189x; 1.1189x over previous
//
#include <hip/hip_runtime.h>
#include <math.h>

#define NR 65536
#define NS 2097152

typedef __attribute__((ext_vector_type(4))) float f32x4;
typedef __attribute__((ext_vector_type(8))) short short8;

#define RSTRIDE 52          // dwords per sample row (48 + 4 pad; 16B-aligned)
#define GSTRIDE (16 * 52 + 4)  // 836 dwords per 16-sample group

// ---------------- workspace layout ----------------
// [0, NS*8)                : uint2 rgba (bf16 r,g | b,alpha) per sample
// [NS*8, +NR*4)            : int start[NR]
// [+NR*4, +NR*4)           : int end[NR]
// [NS*8+NR*8, +40KB)       : uint4 wfrag[40*64]  (A-fragments, bf16, W^T)

// Native bf16 conversion (RNE fptrunc) — compiler lowers to HW cvt.
__device__ __forceinline__ uint packbf(float a, float b) {
    __bf16 lo = (__bf16)a, hi = (__bf16)b;
    ushort ul = __builtin_bit_cast(ushort, lo);
    ushort uh = __builtin_bit_cast(ushort, hi);
    return (uint)ul | ((uint)uh << 16);
}
__device__ __forceinline__ float bflo(uint u) { return __builtin_bit_cast(float, u << 16); }

__global__ void init_bounds(int* __restrict__ start, int* __restrict__ end) {
    int r = blockIdx.x * blockDim.x + threadIdx.x;
    if (r < NR) { start[r] = 0; end[r] = 0; }
}

__global__ void find_bounds(const int* __restrict__ ridx,
                            int* __restrict__ start, int* __restrict__ end) {
    int i = blockIdx.x * blockDim.x + threadIdx.x;
    if (i >= NS) return;
    int r = ridx[i];
    if (i == 0 || ridx[i - 1] != r) start[r] = i;
    if (i == NS - 1 || ridx[i + 1] != r) end[r] = i + 1;
}

// A-fragments = W^T: lane holds A[m = 16ft + (l&15)][k = 32ks + (l>>4)*8 + e]
//             = W[k][16ft + (l&15)].
// Order: L1 0-7 (f = ks*4+ft), L2 8-15, Wf 16-23, Wr1 24-35, Wd 36-37, Wr2 38-39.
__global__ void build_frags(const float* __restrict__ W1, const float* __restrict__ W2,
                            const float* __restrict__ Wf, const float* __restrict__ Wr1,
                            const float* __restrict__ Wd, const float* __restrict__ Wr2,
                            uint4* __restrict__ wfrag) {
    int t = blockIdx.x * blockDim.x + threadIdx.x;
    if (t >= 40 * 64) return;
    int f = t >> 6, lane = t & 63;
    int c = lane & 15;
    uint q[4];
    if (f < 36) {
        const float* W; int kmax, fl;
        if (f < 8)       { W = W1;  kmax = 63; fl = f; }
        else if (f < 16) { W = W2;  kmax = 64; fl = f - 8; }
        else if (f < 24) { W = Wf;  kmax = 64; fl = f - 16; }
        else             { W = Wr1; kmax = 91; fl = f - 24; }
        int ks = fl >> 2, ft = fl & 3;
        int n = ft * 16 + c;
        int kb = ks * 32 + ((lane >> 4) * 8);
        #pragma unroll
        for (int j = 0; j < 4; ++j) {
            int k0 = kb + 2 * j, k1 = k0 + 1;
            float v0 = (k0 < kmax) ? W[k0 * 64 + n] : 0.0f;
            float v1 = (k1 < kmax) ? W[k1 * 64 + n] : 0.0f;
            q[j] = packbf(v0, v1);
        }
    } else if (f < 38) {          // sigma tile: A[m][k] = (m==0) ? Wd[k] : 0
        int kb = (f - 36) * 32 + ((lane >> 4) * 8);
        #pragma unroll
        for (int j = 0; j < 4; ++j) {
            float v0 = (c == 0) ? Wd[kb + 2 * j] : 0.0f;
            float v1 = (c == 0) ? Wd[kb + 2 * j + 1] : 0.0f;
            q[j] = packbf(v0, v1);
        }
    } else {                      // rgb tile: A[m][k] = (m<3) ? Wr2[k*3+m] : 0
        int kb = (f - 38) * 32 + ((lane >> 4) * 8);
        #pragma unroll
        for (int j = 0; j < 4; ++j) {
            float v0 = (c < 3) ? Wr2[(kb + 2 * j) * 3 + c] : 0.0f;
            float v1 = (c < 3) ? Wr2[(kb + 2 * j + 1) * 3 + c] : 0.0f;
            q[j] = packbf(v0, v1);
        }
    }
    wfrag[(size_t)f * 64 + lane] = make_uint4(q[0], q[1], q[2], q[3]);
}

// LDS layout (sample-major, UNSWIZZLED — RSTRIDE=52 gives slot = (13s+g) mod 8,
// 13 odd => perfect 2-lanes-per-16B-slot balance per quarter-wave, which is the
// provable minimum for wave64 on 32 banks; 2-way is free per m136):
//   group st base = (w*4+st)*GSTRIDE; sample row = + s*RSTRIDE (52 dwords).
//   Logical dword c = bf16 feature pair c of that sample, stored at row + c.
//   Dwords 0..31 = activations (64 feats), 32..47 = dir-enc, 48 = dtv.

template <int KS, bool RELU, bool SIGMA>
__device__ __forceinline__ void dense_layer(uint* S, const uint4* __restrict__ wfrag,
                                            int fb, const float* __restrict__ bias,
                                            float bd0, uint rbase, uint wbA, uint wbB,
                                            int lane, float* sigout) {
    const int g = lane >> 4;
    uint4 wf[KS * 4];
    #pragma unroll
    for (int i = 0; i < KS * 4; ++i) wf[i] = wfrag[(size_t)(fb + i) * 64 + lane];
    uint4 wsg[2];
    if constexpr (SIGMA) {
        wsg[0] = wfrag[36 * 64 + lane];
        wsg[1] = wfrag[37 * 64 + lane];
    }
    float4 bfr[4];
    #pragma unroll
    for (int ft = 0; ft < 4; ++ft)
        bfr[ft] = *(const float4*)(bias + 16 * ft + 4 * g);

    #pragma unroll
    for (int st = 0; st < 4; ++st) {
        const uint stoff = (uint)st * (uint)GSTRIDE;
        uint4 B[KS];
        #pragma unroll
        for (int ks = 0; ks < KS; ++ks)
            B[ks] = *(const uint4*)&S[rbase + stoff + 16u * (uint)ks];  // ds_read_b128
        f32x4 acc[4];
        #pragma unroll
        for (int ft = 0; ft < 4; ++ft)
            acc[ft] = (f32x4){bfr[ft].x, bfr[ft].y, bfr[ft].z, bfr[ft].w};
        f32x4 sacc;
        if constexpr (SIGMA) sacc = (f32x4){(g == 0) ? bd0 : 0.0f, 0.0f, 0.0f, 0.0f};
        #pragma unroll
        for (int ks = 0; ks < KS; ++ks) {
            short8 bv = __builtin_bit_cast(short8, B[ks]);
            #pragma unroll
            for (int ft = 0; ft < 4; ++ft)
                acc[ft] = __builtin_amdgcn_mfma_f32_16x16x32_bf16(
                    __builtin_bit_cast(short8, wf[ks * 4 + ft]), bv, acc[ft], 0, 0, 0);
            if constexpr (SIGMA)
                sacc = __builtin_amdgcn_mfma_f32_16x16x32_bf16(
                    __builtin_bit_cast(short8, wsg[ks]), bv, sacc, 0, 0, 0);
        }
        // D layout: col = lane&15 = sample, row = 4g + reg = out-feature.
        // Features 16ft+4g..+3 = logical dwords 8ft+2g, 8ft+2g+1 -> one b64.
        #pragma unroll
        for (int ft = 0; ft < 4; ++ft) {
            float a0 = acc[ft][0], a1 = acc[ft][1], a2 = acc[ft][2], a3 = acc[ft][3];
            if constexpr (RELU) {
                a0 = fmaxf(a0, 0.0f); a1 = fmaxf(a1, 0.0f);
                a2 = fmaxf(a2, 0.0f); a3 = fmaxf(a3, 0.0f);
            }
            uint2 v = make_uint2(packbf(a0, a1), packbf(a2, a3));
            uint base = (ft & 1) ? wbB : wbA;
            *(uint2*)&S[base + stoff + 16u * (uint)(ft >> 1)] = v;      // ds_write_b64
        }
        if constexpr (SIGMA) sigout[st] = sacc[0];
    }
}

__global__ __launch_bounds__(256, 3) void fused_mlp(
    const float* __restrict__ rays_o, const float* __restrict__ viewdirs,
    const float* __restrict__ t_starts, const float* __restrict__ t_ends,
    const float* __restrict__ b1, const float* __restrict__ b2,
    const float* __restrict__ bd, const float* __restrict__ bf_,
    const float* __restrict__ br1, const float* __restrict__ br2,
    const int* __restrict__ ridx, const uint4* __restrict__ wfrag,
    uint2* __restrict__ rgba)
{
    __shared__ uint S[16 * GSTRIDE];   // 13376 dwords = 53504 B -> 3 blocks/CU

    const int tid = threadIdx.x;
    const int w = tid >> 6, lane = tid & 63;
    const int g = lane >> 4, s = lane & 15;
    const uint wgb = (uint)(w * 4) * (uint)GSTRIDE;
    const uint rowcol = wgb + (uint)s * (uint)RSTRIDE;          // group 0 of wave, row s
    const int si = blockIdx.x * 256 + tid;

    int rr = ridx[si];
    float ts = t_starts[si], te = t_ends[si];
    float tm = 0.5f * (ts + te), dtv = te - ts;
    float dx = viewdirs[3 * rr + 0], dy = viewdirs[3 * rr + 1], dz = viewdirs[3 * rr + 2];
    float px = rays_o[3 * rr + 0] + dx * tm;
    float py = rays_o[3 * rr + 1] + dy * tm;
    float pz = rays_o[3 * rr + 2] + dz * tm;

    // Per-thread base registers (all later accesses are base + imm offset):
    const uint ownrow = wgb + (uint)g * (uint)GSTRIDE + (uint)s * (uint)RSTRIDE;
    const uint rbase = rowcol + 4u * (uint)g;
    const uint wbA = rowcol + 2u * (uint)g;
    const uint wbB = wbA + 8u;

    // ---- posenc(pts,10) via double-angle recurrence -> logical dwords 0..31 ----
    {
        float enc[64];
        enc[0] = px; enc[1] = py; enc[2] = pz;
        float sx = __sinf(px), cx = __cosf(px);
        float sy = __sinf(py), cy = __cosf(py);
        float sz = __sinf(pz), cz = __cosf(pz);
        #pragma unroll
        for (int l = 0; l < 10; ++l) {
            enc[3 + 6 * l + 0] = sx; enc[3 + 6 * l + 1] = sy; enc[3 + 6 * l + 2] = sz;
            enc[3 + 6 * l + 3] = cx; enc[3 + 6 * l + 4] = cy; enc[3 + 6 * l + 5] = cz;
            float nsx = 2.0f * sx * cx, nsy = 2.0f * sy * cy, nsz = 2.0f * sz * cz;
            cx = fmaf(-2.0f * sx, sx, 1.0f);
            cy = fmaf(-2.0f * sy, sy, 1.0f);
            cz = fmaf(-2.0f * sz, sz, 1.0f);
            sx = nsx; sy = nsy; sz = nsz;
        }
        enc[63] = 0.0f;
        #pragma unroll
        for (int ch = 0; ch < 8; ++ch) {
            uint4 q = make_uint4(packbf(enc[8 * ch + 0], enc[8 * ch + 1]),
                                 packbf(enc[8 * ch + 2], enc[8 * ch + 3]),
                                 packbf(enc[8 * ch + 4], enc[8 * ch + 5]),
                                 packbf(enc[8 * ch + 6], enc[8 * ch + 7]));
            *(uint4*)&S[ownrow + 4u * (uint)ch] = q;                    // ds_write_b128
        }
    }
    // ---- posenc(d,4) -> logical dwords 32..47 (chunks 8..11) ----
    {
        float de[32];
        de[0] = dx; de[1] = dy; de[2] = dz;
        float sx = __sinf(dx), cx = __cosf(dx);
        float sy = __sinf(dy), cy = __cosf(dy);
        float sz = __sinf(dz), cz = __cosf(dz);
        #pragma unroll
        for (int l = 0; l < 4; ++l) {
            de[3 + 6 * l + 0] = sx; de[3 + 6 * l + 1] = sy; de[3 + 6 * l + 2] = sz;
            de[3 + 6 * l + 3] = cx; de[3 + 6 * l + 4] = cy; de[3 + 6 * l + 5] = cz;
            float nsx = 2.0f * sx * cx, nsy = 2.0f * sy * cy, nsz = 2.0f * sz * cz;
            cx = fmaf(-2.0f * sx, sx, 1.0f);
            cy = fmaf(-2.0f * sy, sy, 1.0f);
            cz = fmaf(-2.0f * sz, sz, 1.0f);
            sx = nsx; sy = nsy; sz = nsz;
        }
        #pragma unroll
        for (int k = 27; k < 32; ++k) de[k] = 0.0f;
        #pragma unroll
        for (int c = 0; c < 4; ++c) {
            uint4 q = make_uint4(packbf(de[8 * c + 0], de[8 * c + 1]),
                                 packbf(de[8 * c + 2], de[8 * c + 3]),
                                 packbf(de[8 * c + 4], de[8 * c + 5]),
                                 packbf(de[8 * c + 6], de[8 * c + 7]));
            *(uint4*)&S[ownrow + 32u + 4u * (uint)c] = q;
        }
    }
    S[ownrow + 48] = __builtin_bit_cast(uint, dtv);                     // dtv in row pad

    float sig4[4];
    float bd0 = bd[0];

    dense_layer<2, true,  false>(S, wfrag,  0, b1,  0.0f, rbase, wbA, wbB, lane, sig4);
    dense_layer<2, true,  false>(S, wfrag,  8, b2,  0.0f, rbase, wbA, wbB, lane, sig4);
    dense_layer<2, false, true >(S, wfrag, 16, bf_, bd0,  rbase, wbA, wbB, lane, sig4);
    dense_layer<3, true,  false>(S, wfrag, 24, br1, 0.0f, rbase, wbA, wbB, lane, sig4);

    // ---- rgb tile + epilogue ----
    {
        uint4 wr0 = wfrag[38 * 64 + lane], wr1f = wfrag[39 * 64 + lane];
        float c0 = br2[0], c1 = br2[1], c2 = br2[2];
        #pragma unroll
        for (int st = 0; st < 4; ++st) {
            const uint stoff = (uint)st * (uint)GSTRIDE;
            uint4 B0 = *(const uint4*)&S[rbase + stoff];           // feat chunks g
            uint4 B1 = *(const uint4*)&S[rbase + stoff + 16u];     // feat chunks 4+g
            f32x4 acc = (g == 0) ? (f32x4){c0, c1, c2, 0.0f}
                                 : (f32x4){0.0f, 0.0f, 0.0f, 0.0f};
            acc = __builtin_amdgcn_mfma_f32_16x16x32_bf16(
                __builtin_bit_cast(short8, wr0), __builtin_bit_cast(short8, B0), acc, 0, 0, 0);
            acc = __builtin_amdgcn_mfma_f32_16x16x32_bf16(
                __builtin_bit_cast(short8, wr1f), __builtin_bit_cast(short8, B1), acc, 0, 0, 0);
            if (lane < 16) {
                float sg = fmaxf(sig4[st], 0.0f);
                float dte = __builtin_bit_cast(float,
                    S[wgb + stoff + (uint)lane * (uint)RSTRIDE + 48u]);
                float alpha = 1.0f - __expf(-sg * dte);
                float r0 = 1.0f / (1.0f + __expf(-acc[0]));
                float r1 = 1.0f / (1.0f + __expf(-acc[1]));
                float r2 = 1.0f / (1.0f + __expf(-acc[2]));
                uint2 o;
                o.x = packbf(r0, r1);
                o.y = packbf(r2, alpha);
                rgba[blockIdx.x * 256 + w * 64 + st * 16 + lane] = o;
            }
        }
    }
}

__global__ void render_kernel(const uint2* __restrict__ rgba,
                              const float* __restrict__ t_starts,
                              const float* __restrict__ t_ends,
                              const int* __restrict__ start,
                              const int* __restrict__ end,
                              float* __restrict__ out)
{
    int r = blockIdx.x * blockDim.x + threadIdx.x;
    if (r >= NR) return;
    int sb = start[r], e = end[r];
    float T = 1.0f, c0 = 0.0f, c1 = 0.0f, c2 = 0.0f, op = 0.0f, dp = 0.0f;
    for (int i = sb; i < e; ++i) {
        uint2 q = rgba[i];
        float vr = bflo(q.x & 0xffffu), vg = bflo(q.x >> 16);
        float vb = bflo(q.y & 0xffffu), va = bflo(q.y >> 16);
        float wgt = T * va;
        float tmid = 0.5f * (t_starts[i] + t_ends[i]);
        c0 += wgt * vr; c1 += wgt * vg; c2 += wgt * vb;
        op += wgt; dp += wgt * tmid;
        T *= (1.0f - va);
    }
    float bg = 1.0f - op;
    c0 += bg; c1 += bg; c2 += bg;
    out[3 * r + 0] = c0;
    out[3 * r + 1] = c1;
    out[3 * r + 2] = c2;
    out[3 * NR + r] = op;
    out[4 * NR + r] = dp;
}

extern "C" void kernel_launch(void* const* d_in, const int* in_sizes, int n_in,
                              void* d_out, int out_size, void* d_ws, size_t ws_size,
                              hipStream_t stream) {
    const float* rays_o   = (const float*)d_in[0];
    const float* viewdirs = (const float*)d_in[1];
    const float* t_starts = (const float*)d_in[2];
    const float* t_ends   = (const float*)d_in[3];
    const float* W1  = (const float*)d_in[4];
    const float* b1  = (const float*)d_in[5];
    const float* W2  = (const float*)d_in[6];
    const float* b2  = (const float*)d_in[7];
    const float* Wd  = (const float*)d_in[8];
    const float* bd  = (const float*)d_in[9];
    const float* Wf  = (const float*)d_in[10];
    const float* bf_ = (const float*)d_in[11];
    const float* Wr1 = (const float*)d_in[12];
    const float* br1 = (const float*)d_in[13];
    const float* Wr2 = (const float*)d_in[14];
    const float* br2 = (const float*)d_in[15];
    const int* ridx  = (const int*)d_in[16];
    float* out = (float*)d_out;

    char* ws = (char*)d_ws;
    uint2* rgba = (uint2*)ws;
    int* start = (int*)(ws + (size_t)NS * 8);
    int* end   = start + NR;
    uint4* wfrag = (uint4*)(ws + (size_t)NS * 8 + (size_t)NR * 8);

    build_frags<<<10, 256, 0, stream>>>(W1, W2, Wf, Wr1, Wd, Wr2, wfrag);
    init_bounds<<<NR / 256, 256, 0, stream>>>(start, end);
    find_bounds<<<NS / 256, 256, 0, stream>>>(ridx, start, end);
    fused_mlp<<<NS / 256, 256, 0, stream>>>(
        rays_o, viewdirs, t_starts, t_ends,
        b1, b2, bd, bf_, br1, br2, ridx, wfrag, rgba);
    render_kernel<<<NR / 256, 256, 0, stream>>>(rgba, t_starts, t_ends, start, end, out);
}

// Round 9
// 159.643 us; speedup vs baseline: 1.1707x; 1.0462x over previous
//
#include <hip/hip_runtime.h>
#include <math.h>

#define NR 65536
#define NS 2097152

typedef __attribute__((ext_vector_type(4))) float f32x4;
typedef __attribute__((ext_vector_type(8))) short short8;

#define RSTRIDE 36             // dwords per sample row (32 act + dtv + sig + 2 pad)
#define GSTRIDE (16 * 36 + 4)  // 580 dwords per 16-sample group

// ---------------- workspace layout ----------------
// [0, NS*8)                     : uint2 rgba (bf16 r,g | b,alpha) per sample
// [NS*8, +NR*8)                 : int start[NR], end[NR]
// [NS*8+NR*8, +40KB)            : uint4 wfrag[40*64]  (A-fragments, bf16, W^T)
// [NS*8+NR*8+40KB, +4MB)        : uint4 dtab[NR*4]    (per-ray dir-enc, bf16)

// Native bf16 conversion (RNE fptrunc) — compiler lowers to HW cvt.
__device__ __forceinline__ uint packbf(float a, float b) {
    __bf16 lo = (__bf16)a, hi = (__bf16)b;
    ushort ul = __builtin_bit_cast(ushort, lo);
    ushort uh = __builtin_bit_cast(ushort, hi);
    return (uint)ul | ((uint)uh << 16);
}
__device__ __forceinline__ float bflo(uint u) { return __builtin_bit_cast(float, u << 16); }

__global__ void init_bounds(int* __restrict__ start, int* __restrict__ end) {
    int r = blockIdx.x * blockDim.x + threadIdx.x;
    if (r < NR) { start[r] = 0; end[r] = 0; }
}

__global__ void find_bounds(const int* __restrict__ ridx,
                            int* __restrict__ start, int* __restrict__ end) {
    int i = blockIdx.x * blockDim.x + threadIdx.x;
    if (i >= NS) return;
    int r = ridx[i];
    if (i == 0 || ridx[i - 1] != r) start[r] = i;
    if (i == NS - 1 || ridx[i + 1] != r) end[r] = i + 1;
}

// Per-ray dir posenc -> bf16-packed 16 dwords (4 uint4) per ray.
__global__ void direnc_kernel(const float* __restrict__ viewdirs,
                              uint4* __restrict__ dtab) {
    int r = blockIdx.x * blockDim.x + threadIdx.x;
    if (r >= NR) return;
    float dx = viewdirs[3 * r + 0], dy = viewdirs[3 * r + 1], dz = viewdirs[3 * r + 2];
    float de[32];
    de[0] = dx; de[1] = dy; de[2] = dz;
    float sx = __sinf(dx), cx = __cosf(dx);
    float sy = __sinf(dy), cy = __cosf(dy);
    float sz = __sinf(dz), cz = __cosf(dz);
    #pragma unroll
    for (int l = 0; l < 4; ++l) {
        de[3 + 6 * l + 0] = sx; de[3 + 6 * l + 1] = sy; de[3 + 6 * l + 2] = sz;
        de[3 + 6 * l + 3] = cx; de[3 + 6 * l + 4] = cy; de[3 + 6 * l + 5] = cz;
        float nsx = 2.0f * sx * cx, nsy = 2.0f * sy * cy, nsz = 2.0f * sz * cz;
        cx = fmaf(-2.0f * sx, sx, 1.0f);
        cy = fmaf(-2.0f * sy, sy, 1.0f);
        cz = fmaf(-2.0f * sz, sz, 1.0f);
        sx = nsx; sy = nsy; sz = nsz;
    }
    #pragma unroll
    for (int k = 27; k < 32; ++k) de[k] = 0.0f;
    #pragma unroll
    for (int c = 0; c < 4; ++c) {
        uint4 q = make_uint4(packbf(de[8 * c + 0], de[8 * c + 1]),
                             packbf(de[8 * c + 2], de[8 * c + 3]),
                             packbf(de[8 * c + 4], de[8 * c + 5]),
                             packbf(de[8 * c + 6], de[8 * c + 7]));
        dtab[(size_t)r * 4 + c] = q;
    }
}

// A-fragments = W^T: lane holds A[m = 16ft + (l&15)][k = 32ks + (l>>4)*8 + e]
//             = W[k][16ft + (l&15)].
// Order: L1 0-7 (f = ks*4+ft), L2 8-15, Wf 16-23, Wr1 24-35, Wd 36-37, Wr2 38-39.
__global__ void build_frags(const float* __restrict__ W1, const float* __restrict__ W2,
                            const float* __restrict__ Wf, const float* __restrict__ Wr1,
                            const float* __restrict__ Wd, const float* __restrict__ Wr2,
                            uint4* __restrict__ wfrag) {
    int t = blockIdx.x * blockDim.x + threadIdx.x;
    if (t >= 40 * 64) return;
    int f = t >> 6, lane = t & 63;
    int c = lane & 15;
    uint q[4];
    if (f < 36) {
        const float* W; int kmax, fl;
        if (f < 8)       { W = W1;  kmax = 63; fl = f; }
        else if (f < 16) { W = W2;  kmax = 64; fl = f - 8; }
        else if (f < 24) { W = Wf;  kmax = 64; fl = f - 16; }
        else             { W = Wr1; kmax = 91; fl = f - 24; }
        int ks = fl >> 2, ft = fl & 3;
        int n = ft * 16 + c;
        int kb = ks * 32 + ((lane >> 4) * 8);
        #pragma unroll
        for (int j = 0; j < 4; ++j) {
            int k0 = kb + 2 * j, k1 = k0 + 1;
            float v0 = (k0 < kmax) ? W[k0 * 64 + n] : 0.0f;
            float v1 = (k1 < kmax) ? W[k1 * 64 + n] : 0.0f;
            q[j] = packbf(v0, v1);
        }
    } else if (f < 38) {          // sigma tile: A[m][k] = (m==0) ? Wd[k] : 0
        int kb = (f - 36) * 32 + ((lane >> 4) * 8);
        #pragma unroll
        for (int j = 0; j < 4; ++j) {
            float v0 = (c == 0) ? Wd[kb + 2 * j] : 0.0f;
            float v1 = (c == 0) ? Wd[kb + 2 * j + 1] : 0.0f;
            q[j] = packbf(v0, v1);
        }
    } else {                      // rgb tile: A[m][k] = (m<3) ? Wr2[k*3+m] : 0
        int kb = (f - 38) * 32 + ((lane >> 4) * 8);
        #pragma unroll
        for (int j = 0; j < 4; ++j) {
            float v0 = (c < 3) ? Wr2[(kb + 2 * j) * 3 + c] : 0.0f;
            float v1 = (c < 3) ? Wr2[(kb + 2 * j + 1) * 3 + c] : 0.0f;
            q[j] = packbf(v0, v1);
        }
    }
    wfrag[(size_t)f * 64 + lane] = make_uint4(q[0], q[1], q[2], q[3]);
}

// LDS layout (sample-major, unswizzled; RSTRIDE=36 => 9 chunks/row, 9 odd =>
// b128 slot map (9s+g) mod 8 is perfectly 2-lane-balanced per quarter-wave):
//   group st base = (w*4+st)*GSTRIDE; sample row = + s*RSTRIDE.
//   Dwords 0..31 = activations (64 feats bf16), 32 = dtv, 33 = sigma.

template <int KS, bool RELU, bool SIGMA, bool DIRB>
__device__ __forceinline__ void dense_layer(uint* S, const uint4* __restrict__ wfrag,
                                            int fb, const float* __restrict__ bias,
                                            float bd0, uint rbase, uint wbA, uint wbB,
                                            int lane, const uint4 (&dirB)[4]) {
    const int g = lane >> 4;
    uint4 wf[KS * 4];
    #pragma unroll
    for (int i = 0; i < KS * 4; ++i) wf[i] = wfrag[(size_t)(fb + i) * 64 + lane];
    uint4 wsg[2];
    if constexpr (SIGMA) {
        wsg[0] = wfrag[36 * 64 + lane];
        wsg[1] = wfrag[37 * 64 + lane];
    }
    float4 bfr[4];
    #pragma unroll
    for (int ft = 0; ft < 4; ++ft)
        bfr[ft] = *(const float4*)(bias + 16 * ft + 4 * g);

    #pragma unroll
    for (int st = 0; st < 4; ++st) {
        const uint stoff = (uint)st * (uint)GSTRIDE;
        uint4 B[KS];
        #pragma unroll
        for (int ks = 0; ks < KS; ++ks) {
            if (DIRB && ks == KS - 1) B[ks] = dirB[st];
            else B[ks] = *(const uint4*)&S[rbase + stoff + 16u * (uint)ks];  // ds_read_b128
        }
        f32x4 acc[4];
        #pragma unroll
        for (int ft = 0; ft < 4; ++ft)
            acc[ft] = (f32x4){bfr[ft].x, bfr[ft].y, bfr[ft].z, bfr[ft].w};
        f32x4 sacc;
        if constexpr (SIGMA) sacc = (f32x4){(g == 0) ? bd0 : 0.0f, 0.0f, 0.0f, 0.0f};
        #pragma unroll
        for (int ks = 0; ks < KS; ++ks) {
            short8 bv = __builtin_bit_cast(short8, B[ks]);
            #pragma unroll
            for (int ft = 0; ft < 4; ++ft)
                acc[ft] = __builtin_amdgcn_mfma_f32_16x16x32_bf16(
                    __builtin_bit_cast(short8, wf[ks * 4 + ft]), bv, acc[ft], 0, 0, 0);
            if constexpr (SIGMA)
                sacc = __builtin_amdgcn_mfma_f32_16x16x32_bf16(
                    __builtin_bit_cast(short8, wsg[ks]), bv, sacc, 0, 0, 0);
        }
        // D layout: col = lane&15 = sample, row = 4g + reg = out-feature.
        #pragma unroll
        for (int ft = 0; ft < 4; ++ft) {
            float a0 = acc[ft][0], a1 = acc[ft][1], a2 = acc[ft][2], a3 = acc[ft][3];
            if constexpr (RELU) {
                a0 = fmaxf(a0, 0.0f); a1 = fmaxf(a1, 0.0f);
                a2 = fmaxf(a2, 0.0f); a3 = fmaxf(a3, 0.0f);
            }
            uint2 v = make_uint2(packbf(a0, a1), packbf(a2, a3));
            uint base = (ft & 1) ? wbB : wbA;
            *(uint2*)&S[base + stoff + 16u * (uint)(ft >> 1)] = v;      // ds_write_b64
        }
        if constexpr (SIGMA) {
            if (g == 0) S[rbase + stoff + 33u] = __builtin_bit_cast(uint, sacc[0]);
        }
    }
}

__global__ __launch_bounds__(256, 4) void fused_mlp(
    const float* __restrict__ rays_o, const float* __restrict__ viewdirs,
    const float* __restrict__ t_starts, const float* __restrict__ t_ends,
    const float* __restrict__ b1, const float* __restrict__ b2,
    const float* __restrict__ bd, const float* __restrict__ bf_,
    const float* __restrict__ br1, const float* __restrict__ br2,
    const int* __restrict__ ridx, const uint4* __restrict__ wfrag,
    const uint4* __restrict__ dtab, uint2* __restrict__ rgba)
{
    __shared__ uint S[16 * GSTRIDE];   // 9280 dwords = 37120 B -> 4 blocks/CU

    const int tid = threadIdx.x;
    const int w = tid >> 6, lane = tid & 63;
    const int g = lane >> 4, s = lane & 15;
    const uint wgb = (uint)(w * 4) * (uint)GSTRIDE;
    const uint rowcol = wgb + (uint)s * (uint)RSTRIDE;
    const int sb0 = blockIdx.x * 256 + w * 64;

    // ---- ridx for this thread's 4 B-samples (st, s) + own sample (st=g) ----
    int ridx4[4];
    #pragma unroll
    for (int st = 0; st < 4; ++st) ridx4[st] = ridx[sb0 + st * 16 + s];
    uint4 dirB[4];
    #pragma unroll
    for (int st = 0; st < 4; ++st) dirB[st] = dtab[(size_t)ridx4[st] * 4 + g];

    const int si = sb0 + g * 16 + s;
    const int rr = ridx4[g];
    float ts = t_starts[si], te = t_ends[si];
    float tm = 0.5f * (ts + te), dtv = te - ts;
    float dx = viewdirs[3 * rr + 0], dy = viewdirs[3 * rr + 1], dz = viewdirs[3 * rr + 2];
    float px = rays_o[3 * rr + 0] + dx * tm;
    float py = rays_o[3 * rr + 1] + dy * tm;
    float pz = rays_o[3 * rr + 2] + dz * tm;

    // Per-thread base registers:
    const uint ownrow = wgb + (uint)g * (uint)GSTRIDE + (uint)s * (uint)RSTRIDE;
    const uint rbase = rowcol + 4u * (uint)g;
    const uint wbA = rowcol + 2u * (uint)g;
    const uint wbB = wbA + 8u;

    // ---- posenc(pts,10) via double-angle recurrence -> logical dwords 0..31 ----
    {
        float enc[64];
        enc[0] = px; enc[1] = py; enc[2] = pz;
        float sx = __sinf(px), cx = __cosf(px);
        float sy = __sinf(py), cy = __cosf(py);
        float sz = __sinf(pz), cz = __cosf(pz);
        #pragma unroll
        for (int l = 0; l < 10; ++l) {
            enc[3 + 6 * l + 0] = sx; enc[3 + 6 * l + 1] = sy; enc[3 + 6 * l + 2] = sz;
            enc[3 + 6 * l + 3] = cx; enc[3 + 6 * l + 4] = cy; enc[3 + 6 * l + 5] = cz;
            float nsx = 2.0f * sx * cx, nsy = 2.0f * sy * cy, nsz = 2.0f * sz * cz;
            cx = fmaf(-2.0f * sx, sx, 1.0f);
            cy = fmaf(-2.0f * sy, sy, 1.0f);
            cz = fmaf(-2.0f * sz, sz, 1.0f);
            sx = nsx; sy = nsy; sz = nsz;
        }
        enc[63] = 0.0f;
        #pragma unroll
        for (int ch = 0; ch < 8; ++ch) {
            uint4 q = make_uint4(packbf(enc[8 * ch + 0], enc[8 * ch + 1]),
                                 packbf(enc[8 * ch + 2], enc[8 * ch + 3]),
                                 packbf(enc[8 * ch + 4], enc[8 * ch + 5]),
                                 packbf(enc[8 * ch + 6], enc[8 * ch + 7]));
            *(uint4*)&S[ownrow + 4u * (uint)ch] = q;                    // ds_write_b128
        }
    }
    S[ownrow + 32] = __builtin_bit_cast(uint, dtv);                     // dtv in row pad

    float bd0 = bd[0];
    uint4 dummy[4];

    dense_layer<2, true,  false, false>(S, wfrag,  0, b1,  0.0f, rbase, wbA, wbB, lane, dummy);
    dense_layer<2, true,  false, false>(S, wfrag,  8, b2,  0.0f, rbase, wbA, wbB, lane, dummy);
    dense_layer<2, false, true,  false>(S, wfrag, 16, bf_, bd0,  rbase, wbA, wbB, lane, dummy);
    dense_layer<3, true,  false, true >(S, wfrag, 24, br1, 0.0f, rbase, wbA, wbB, lane, dirB);

    // ---- rgb tile + epilogue ----
    {
        uint4 wr0 = wfrag[38 * 64 + lane], wr1f = wfrag[39 * 64 + lane];
        float c0 = br2[0], c1 = br2[1], c2 = br2[2];
        #pragma unroll
        for (int st = 0; st < 4; ++st) {
            const uint stoff = (uint)st * (uint)GSTRIDE;
            uint4 B0 = *(const uint4*)&S[rbase + stoff];           // feat chunks g
            uint4 B1 = *(const uint4*)&S[rbase + stoff + 16u];     // feat chunks 4+g
            f32x4 acc = (g == 0) ? (f32x4){c0, c1, c2, 0.0f}
                                 : (f32x4){0.0f, 0.0f, 0.0f, 0.0f};
            acc = __builtin_amdgcn_mfma_f32_16x16x32_bf16(
                __builtin_bit_cast(short8, wr0), __builtin_bit_cast(short8, B0), acc, 0, 0, 0);
            acc = __builtin_amdgcn_mfma_f32_16x16x32_bf16(
                __builtin_bit_cast(short8, wr1f), __builtin_bit_cast(short8, B1), acc, 0, 0, 0);
            if (lane < 16) {
                // g==0 here, so rbase == rowcol: pad dwords of row (st, lane).
                float sg = fmaxf(__builtin_bit_cast(float, S[rbase + stoff + 33u]), 0.0f);
                float dte = __builtin_bit_cast(float, S[rbase + stoff + 32u]);
                float alpha = 1.0f - __expf(-sg * dte);
                float r0 = 1.0f / (1.0f + __expf(-acc[0]));
                float r1 = 1.0f / (1.0f + __expf(-acc[1]));
                float r2 = 1.0f / (1.0f + __expf(-acc[2]));
                uint2 o;
                o.x = packbf(r0, r1);
                o.y = packbf(r2, alpha);
                rgba[sb0 + st * 16 + lane] = o;
            }
        }
    }
}

__global__ void render_kernel(const uint2* __restrict__ rgba,
                              const float* __restrict__ t_starts,
                              const float* __restrict__ t_ends,
                              const int* __restrict__ start,
                              const int* __restrict__ end,
                              float* __restrict__ out)
{
    int r = blockIdx.x * blockDim.x + threadIdx.x;
    if (r >= NR) return;
    int sb = start[r], e = end[r];
    float T = 1.0f, c0 = 0.0f, c1 = 0.0f, c2 = 0.0f, op = 0.0f, dp = 0.0f;
    for (int i = sb; i < e; ++i) {
        uint2 q = rgba[i];
        float vr = bflo(q.x & 0xffffu), vg = bflo(q.x >> 16);
        float vb = bflo(q.y & 0xffffu), va = bflo(q.y >> 16);
        float wgt = T * va;
        float tmid = 0.5f * (t_starts[i] + t_ends[i]);
        c0 += wgt * vr; c1 += wgt * vg; c2 += wgt * vb;
        op += wgt; dp += wgt * tmid;
        T *= (1.0f - va);
    }
    float bg = 1.0f - op;
    c0 += bg; c1 += bg; c2 += bg;
    out[3 * r + 0] = c0;
    out[3 * r + 1] = c1;
    out[3 * r + 2] = c2;
    out[3 * NR + r] = op;
    out[4 * NR + r] = dp;
}

extern "C" void kernel_launch(void* const* d_in, const int* in_sizes, int n_in,
                              void* d_out, int out_size, void* d_ws, size_t ws_size,
                              hipStream_t stream) {
    const float* rays_o   = (const float*)d_in[0];
    const float* viewdirs = (const float*)d_in[1];
    const float* t_starts = (const float*)d_in[2];
    const float* t_ends   = (const float*)d_in[3];
    const float* W1  = (const float*)d_in[4];
    const float* b1  = (const float*)d_in[5];
    const float* W2  = (const float*)d_in[6];
    const float* b2  = (const float*)d_in[7];
    const float* Wd  = (const float*)d_in[8];
    const float* bd  = (const float*)d_in[9];
    const float* Wf  = (const float*)d_in[10];
    const float* bf_ = (const float*)d_in[11];
    const float* Wr1 = (const float*)d_in[12];
    const float* br1 = (const float*)d_in[13];
    const float* Wr2 = (const float*)d_in[14];
    const float* br2 = (const float*)d_in[15];
    const int* ridx  = (const int*)d_in[16];
    float* out = (float*)d_out;

    char* ws = (char*)d_ws;
    uint2* rgba = (uint2*)ws;
    int* start = (int*)(ws + (size_t)NS * 8);
    int* end   = start + NR;
    uint4* wfrag = (uint4*)(ws + (size_t)NS * 8 + (size_t)NR * 8);
    uint4* dtab  = (uint4*)(ws + (size_t)NS * 8 + (size_t)NR * 8 + 40 * 64 * 16);

    build_frags<<<10, 256, 0, stream>>>(W1, W2, Wf, Wr1, Wd, Wr2, wfrag);
    direnc_kernel<<<NR / 256, 256, 0, stream>>>(viewdirs, dtab);
    init_bounds<<<NR / 256, 256, 0, stream>>>(start, end);
    find_bounds<<<NS / 256, 256, 0, stream>>>(ridx, start, end);
    fused_mlp<<<NS / 256, 256, 0, stream>>>(
        rays_o, viewdirs, t_starts, t_ends,
        b1, b2, bd, bf_, br1, br2, ridx, wfrag, dtab, rgba);
    render_kernel<<<NR / 256, 256, 0, stream>>>(rgba, t_starts, t_ends, start, end, out);
}

// Round 10
// 144.640 us; speedup vs baseline: 1.2921x; 1.1037x over previous
//
#include <hip/hip_runtime.h>
#include <math.h>

#define NR 65536
#define NS 2097152

typedef __attribute__((ext_vector_type(4))) float f32x4;
typedef __attribute__((ext_vector_type(2))) float f32x2;
typedef __attribute__((ext_vector_type(8))) short short8;

#define RSTRIDE 36             // dwords per sample row (32 act + dtv + sig + 2 pad)
#define GSTRIDE (16 * 36 + 4)  // 580 dwords per 16-sample group

// ---------------- workspace layout ----------------
// [0, NS*8)                 : uint2 rgba (bf16 r,g | b,alpha) per sample
// [NS*8, +NS*4)             : float tmid[NS]
// [NS*12, +NR*8)            : int start[NR], end[NR]
// [NS*12+NR*8, +40KB)       : uint4 wfrag[40*64]  (A-fragments, bf16, W^T)
// [.. +40KB, +4MB)          : uint4 dtab[NR*4]    (per-ray dir-enc, bf16)

// Native bf16 conversion (RNE fptrunc) — compiler lowers to HW cvt.
__device__ __forceinline__ uint packbf(float a, float b) {
    __bf16 lo = (__bf16)a, hi = (__bf16)b;
    ushort ul = __builtin_bit_cast(ushort, lo);
    ushort uh = __builtin_bit_cast(ushort, hi);
    return (uint)ul | ((uint)uh << 16);
}
__device__ __forceinline__ float bflo(uint u) { return __builtin_bit_cast(float, u << 16); }

__global__ void find_bounds(const int* __restrict__ ridx,
                            int* __restrict__ start, int* __restrict__ end) {
    int i = blockIdx.x * blockDim.x + threadIdx.x;
    if (i >= NS) return;
    int r = ridx[i];
    if (i == 0 || ridx[i - 1] != r) start[r] = i;
    if (i == NS - 1 || ridx[i + 1] != r) end[r] = i + 1;
}

// Merged setup: blocks 0-255 direnc, 256-511 init_bounds, 512-521 build_frags.
__global__ void setup_kernel(const float* __restrict__ viewdirs,
                             uint4* __restrict__ dtab,
                             int* __restrict__ start, int* __restrict__ end,
                             const float* __restrict__ W1, const float* __restrict__ W2,
                             const float* __restrict__ Wf, const float* __restrict__ Wr1,
                             const float* __restrict__ Wd, const float* __restrict__ Wr2,
                             uint4* __restrict__ wfrag) {
    int b = blockIdx.x, tid = threadIdx.x;
    if (b < 256) {
        // ---- per-ray dir posenc -> 4 uint4 per ray ----
        int r = b * 256 + tid;
        float dx = viewdirs[3 * r + 0], dy = viewdirs[3 * r + 1], dz = viewdirs[3 * r + 2];
        float de[32];
        de[0] = dx; de[1] = dy; de[2] = dz;
        float sx = __sinf(dx), cx = __cosf(dx);
        float sy = __sinf(dy), cy = __cosf(dy);
        float sz = __sinf(dz), cz = __cosf(dz);
        #pragma unroll
        for (int l = 0; l < 4; ++l) {
            de[3 + 6 * l + 0] = sx; de[3 + 6 * l + 1] = sy; de[3 + 6 * l + 2] = sz;
            de[3 + 6 * l + 3] = cx; de[3 + 6 * l + 4] = cy; de[3 + 6 * l + 5] = cz;
            float nsx = 2.0f * sx * cx, nsy = 2.0f * sy * cy, nsz = 2.0f * sz * cz;
            cx = fmaf(-2.0f * sx, sx, 1.0f);
            cy = fmaf(-2.0f * sy, sy, 1.0f);
            cz = fmaf(-2.0f * sz, sz, 1.0f);
            sx = nsx; sy = nsy; sz = nsz;
        }
        #pragma unroll
        for (int k = 27; k < 32; ++k) de[k] = 0.0f;
        #pragma unroll
        for (int c = 0; c < 4; ++c) {
            uint4 q = make_uint4(packbf(de[8 * c + 0], de[8 * c + 1]),
                                 packbf(de[8 * c + 2], de[8 * c + 3]),
                                 packbf(de[8 * c + 4], de[8 * c + 5]),
                                 packbf(de[8 * c + 6], de[8 * c + 7]));
            dtab[(size_t)r * 4 + c] = q;
        }
    } else if (b < 512) {
        int r = (b - 256) * 256 + tid;
        start[r] = 0; end[r] = 0;
    } else {
        // ---- build A-fragments (W^T), order: L1 0-7, L2 8-15, Wf 16-23,
        //      Wr1 24-35, Wd 36-37, Wr2 38-39 ----
        int t = (b - 512) * 256 + tid;
        if (t >= 40 * 64) return;
        int f = t >> 6, lane = t & 63;
        int c = lane & 15;
        uint q[4];
        if (f < 36) {
            const float* W; int kmax, fl;
            if (f < 8)       { W = W1;  kmax = 63; fl = f; }
            else if (f < 16) { W = W2;  kmax = 64; fl = f - 8; }
            else if (f < 24) { W = Wf;  kmax = 64; fl = f - 16; }
            else             { W = Wr1; kmax = 91; fl = f - 24; }
            int ks = fl >> 2, ft = fl & 3;
            int n = ft * 16 + c;
            int kb = ks * 32 + ((lane >> 4) * 8);
            #pragma unroll
            for (int j = 0; j < 4; ++j) {
                int k0 = kb + 2 * j, k1 = k0 + 1;
                float v0 = (k0 < kmax) ? W[k0 * 64 + n] : 0.0f;
                float v1 = (k1 < kmax) ? W[k1 * 64 + n] : 0.0f;
                q[j] = packbf(v0, v1);
            }
        } else if (f < 38) {          // sigma tile: A[m][k] = (m==0) ? Wd[k] : 0
            int kb = (f - 36) * 32 + ((lane >> 4) * 8);
            #pragma unroll
            for (int j = 0; j < 4; ++j) {
                float v0 = (c == 0) ? Wd[kb + 2 * j] : 0.0f;
                float v1 = (c == 0) ? Wd[kb + 2 * j + 1] : 0.0f;
                q[j] = packbf(v0, v1);
            }
        } else {                      // rgb tile: A[m][k] = (m<3) ? Wr2[k*3+m] : 0
            int kb = (f - 38) * 32 + ((lane >> 4) * 8);
            #pragma unroll
            for (int j = 0; j < 4; ++j) {
                float v0 = (c < 3) ? Wr2[(kb + 2 * j) * 3 + c] : 0.0f;
                float v1 = (c < 3) ? Wr2[(kb + 2 * j + 1) * 3 + c] : 0.0f;
                q[j] = packbf(v0, v1);
            }
        }
        wfrag[(size_t)f * 64 + lane] = make_uint4(q[0], q[1], q[2], q[3]);
    }
}

// LDS layout (sample-major, unswizzled; RSTRIDE=36 => 9 chunks/row, 9 odd =>
// b128 slot map (9s+g) mod 8 is perfectly 2-lane-balanced per quarter-wave):
//   group st base = (w*4+st)*GSTRIDE; sample row = + s*RSTRIDE.
//   Dwords 0..31 = activations (64 feats bf16), 32 = dtv, 33 = sigma.

template <int KS, bool RELU, bool SIGMA, bool DIRB>
__device__ __forceinline__ void dense_layer(uint* S, const uint4* __restrict__ wfrag,
                                            int fb, const float* __restrict__ bias,
                                            float bd0, uint rbase, uint wbA, uint wbB,
                                            int lane, const uint4 (&dirB)[4]) {
    const int g = lane >> 4;
    uint4 wf[KS * 4];
    #pragma unroll
    for (int i = 0; i < KS * 4; ++i) wf[i] = wfrag[(size_t)(fb + i) * 64 + lane];
    uint4 wsg[2];
    if constexpr (SIGMA) {
        wsg[0] = wfrag[36 * 64 + lane];
        wsg[1] = wfrag[37 * 64 + lane];
    }
    float4 bfr[4];
    #pragma unroll
    for (int ft = 0; ft < 4; ++ft)
        bfr[ft] = *(const float4*)(bias + 16 * ft + 4 * g);

    #pragma unroll
    for (int st = 0; st < 4; ++st) {
        const uint stoff = (uint)st * (uint)GSTRIDE;
        uint4 B[KS];
        #pragma unroll
        for (int ks = 0; ks < KS; ++ks) {
            if (DIRB && ks == KS - 1) B[ks] = dirB[st];
            else B[ks] = *(const uint4*)&S[rbase + stoff + 16u * (uint)ks];  // ds_read_b128
        }
        f32x4 acc[4];
        #pragma unroll
        for (int ft = 0; ft < 4; ++ft)
            acc[ft] = (f32x4){bfr[ft].x, bfr[ft].y, bfr[ft].z, bfr[ft].w};
        f32x4 sacc;
        if constexpr (SIGMA) sacc = (f32x4){(g == 0) ? bd0 : 0.0f, 0.0f, 0.0f, 0.0f};
        __builtin_amdgcn_s_setprio(1);
        #pragma unroll
        for (int ks = 0; ks < KS; ++ks) {
            short8 bv = __builtin_bit_cast(short8, B[ks]);
            #pragma unroll
            for (int ft = 0; ft < 4; ++ft)
                acc[ft] = __builtin_amdgcn_mfma_f32_16x16x32_bf16(
                    __builtin_bit_cast(short8, wf[ks * 4 + ft]), bv, acc[ft], 0, 0, 0);
            if constexpr (SIGMA)
                sacc = __builtin_amdgcn_mfma_f32_16x16x32_bf16(
                    __builtin_bit_cast(short8, wsg[ks]), bv, sacc, 0, 0, 0);
        }
        __builtin_amdgcn_s_setprio(0);
        // D layout: col = lane&15 = sample, row = 4g + reg = out-feature.
        #pragma unroll
        for (int ft = 0; ft < 4; ++ft) {
            float a0 = acc[ft][0], a1 = acc[ft][1], a2 = acc[ft][2], a3 = acc[ft][3];
            if constexpr (RELU) {
                a0 = fmaxf(a0, 0.0f); a1 = fmaxf(a1, 0.0f);
                a2 = fmaxf(a2, 0.0f); a3 = fmaxf(a3, 0.0f);
            }
            uint2 v = make_uint2(packbf(a0, a1), packbf(a2, a3));
            uint base = (ft & 1) ? wbB : wbA;
            *(uint2*)&S[base + stoff + 16u * (uint)(ft >> 1)] = v;      // ds_write_b64
        }
        if constexpr (SIGMA) {
            if (g == 0) S[rbase + stoff + 33u] = __builtin_bit_cast(uint, sacc[0]);
        }
    }
}

__global__ __launch_bounds__(256, 4) void fused_mlp(
    const float* __restrict__ rays_o, const float* __restrict__ viewdirs,
    const float* __restrict__ t_starts, const float* __restrict__ t_ends,
    const float* __restrict__ b1, const float* __restrict__ b2,
    const float* __restrict__ bd, const float* __restrict__ bf_,
    const float* __restrict__ br1, const float* __restrict__ br2,
    const int* __restrict__ ridx, const uint4* __restrict__ wfrag,
    const uint4* __restrict__ dtab, uint2* __restrict__ rgba,
    float* __restrict__ tmarr)
{
    __shared__ uint S[16 * GSTRIDE];   // 9280 dwords = 37120 B -> 4 blocks/CU

    const int tid = threadIdx.x;
    const int w = tid >> 6, lane = tid & 63;
    const int g = lane >> 4, s = lane & 15;
    const uint wgb = (uint)(w * 4) * (uint)GSTRIDE;
    const uint rowcol = wgb + (uint)s * (uint)RSTRIDE;
    const int sb0 = blockIdx.x * 256 + w * 64;

    // ---- ridx for this thread's 4 B-samples (st, s) + own sample (st=g) ----
    int ridx4[4];
    #pragma unroll
    for (int st = 0; st < 4; ++st) ridx4[st] = ridx[sb0 + st * 16 + s];
    uint4 dirB[4];
    #pragma unroll
    for (int st = 0; st < 4; ++st) dirB[st] = dtab[(size_t)ridx4[st] * 4 + g];

    const int si = sb0 + g * 16 + s;
    const int rr = ridx4[g];
    float ts = t_starts[si], te = t_ends[si];
    float tm = 0.5f * (ts + te), dtv = te - ts;
    float dx = viewdirs[3 * rr + 0], dy = viewdirs[3 * rr + 1], dz = viewdirs[3 * rr + 2];
    float px = rays_o[3 * rr + 0] + dx * tm;
    float py = rays_o[3 * rr + 1] + dy * tm;
    float pz = rays_o[3 * rr + 2] + dz * tm;
    tmarr[si] = tm;                                   // render reads this (coalesced)

    // Per-thread base registers:
    const uint ownrow = wgb + (uint)g * (uint)GSTRIDE + (uint)s * (uint)RSTRIDE;
    const uint rbase = rowcol + 4u * (uint)g;
    const uint wbA = rowcol + 2u * (uint)g;
    const uint wbB = wbA + 8u;

    // ---- posenc(pts,10), x/y packed (v_pk_* f32), z scalar ----
    {
        float enc[64];
        enc[0] = px; enc[1] = py; enc[2] = pz;
        f32x2 sxy = {__sinf(px), __sinf(py)};
        f32x2 cxy = {__cosf(px), __cosf(py)};
        float sz = __sinf(pz), cz = __cosf(pz);
        #pragma unroll
        for (int l = 0; l < 10; ++l) {
            enc[3 + 6 * l + 0] = sxy.x; enc[3 + 6 * l + 1] = sxy.y; enc[3 + 6 * l + 2] = sz;
            enc[3 + 6 * l + 3] = cxy.x; enc[3 + 6 * l + 4] = cxy.y; enc[3 + 6 * l + 5] = cz;
            f32x2 nsxy = 2.0f * sxy * cxy;
            cxy = 1.0f - 2.0f * sxy * sxy;
            float nsz = 2.0f * sz * cz;
            cz = fmaf(-2.0f * sz, sz, 1.0f);
            sxy = nsxy; sz = nsz;
        }
        enc[63] = 0.0f;
        #pragma unroll
        for (int ch = 0; ch < 8; ++ch) {
            uint4 q = make_uint4(packbf(enc[8 * ch + 0], enc[8 * ch + 1]),
                                 packbf(enc[8 * ch + 2], enc[8 * ch + 3]),
                                 packbf(enc[8 * ch + 4], enc[8 * ch + 5]),
                                 packbf(enc[8 * ch + 6], enc[8 * ch + 7]));
            *(uint4*)&S[ownrow + 4u * (uint)ch] = q;                    // ds_write_b128
        }
    }
    S[ownrow + 32] = __builtin_bit_cast(uint, dtv);                     // dtv in row pad

    float bd0 = bd[0];
    uint4 dummy[4];

    dense_layer<2, true,  false, false>(S, wfrag,  0, b1,  0.0f, rbase, wbA, wbB, lane, dummy);
    dense_layer<2, true,  false, false>(S, wfrag,  8, b2,  0.0f, rbase, wbA, wbB, lane, dummy);
    dense_layer<2, false, true,  false>(S, wfrag, 16, bf_, bd0,  rbase, wbA, wbB, lane, dummy);
    dense_layer<3, true,  false, true >(S, wfrag, 24, br1, 0.0f, rbase, wbA, wbB, lane, dirB);

    // ---- rgb tile + epilogue ----
    {
        uint4 wr0 = wfrag[38 * 64 + lane], wr1f = wfrag[39 * 64 + lane];
        float c0 = br2[0], c1 = br2[1], c2 = br2[2];
        #pragma unroll
        for (int st = 0; st < 4; ++st) {
            const uint stoff = (uint)st * (uint)GSTRIDE;
            uint4 B0 = *(const uint4*)&S[rbase + stoff];           // feat chunks g
            uint4 B1 = *(const uint4*)&S[rbase + stoff + 16u];     // feat chunks 4+g
            f32x4 acc = (g == 0) ? (f32x4){c0, c1, c2, 0.0f}
                                 : (f32x4){0.0f, 0.0f, 0.0f, 0.0f};
            acc = __builtin_amdgcn_mfma_f32_16x16x32_bf16(
                __builtin_bit_cast(short8, wr0), __builtin_bit_cast(short8, B0), acc, 0, 0, 0);
            acc = __builtin_amdgcn_mfma_f32_16x16x32_bf16(
                __builtin_bit_cast(short8, wr1f), __builtin_bit_cast(short8, B1), acc, 0, 0, 0);
            if (lane < 16) {
                // g==0 here, so rbase == rowcol: pad dwords of row (st, lane).
                uint2 meta = *(const uint2*)&S[rbase + stoff + 32u];   // {dtv, sigma}
                float dte = __builtin_bit_cast(float, meta.x);
                float sg = fmaxf(__builtin_bit_cast(float, meta.y), 0.0f);
                float alpha = 1.0f - __expf(-sg * dte);
                float r0 = 1.0f / (1.0f + __expf(-acc[0]));
                float r1 = 1.0f / (1.0f + __expf(-acc[1]));
                float r2 = 1.0f / (1.0f + __expf(-acc[2]));
                uint2 o;
                o.x = packbf(r0, r1);
                o.y = packbf(r2, alpha);
                rgba[sb0 + st * 16 + lane] = o;
            }
        }
    }
}

__global__ void render_kernel(const uint2* __restrict__ rgba,
                              const float* __restrict__ tmarr,
                              const int* __restrict__ start,
                              const int* __restrict__ end,
                              float* __restrict__ out)
{
    int r = blockIdx.x * blockDim.x + threadIdx.x;
    if (r >= NR) return;
    int sb = start[r], e = end[r];
    float T = 1.0f, c0 = 0.0f, c1 = 0.0f, c2 = 0.0f, op = 0.0f, dp = 0.0f;
    for (int i = sb; i < e; ++i) {
        uint2 q = rgba[i];
        float tmid = tmarr[i];
        float vr = bflo(q.x & 0xffffu), vg = bflo(q.x >> 16);
        float vb = bflo(q.y & 0xffffu), va = bflo(q.y >> 16);
        float wgt = T * va;
        c0 += wgt * vr; c1 += wgt * vg; c2 += wgt * vb;
        op += wgt; dp += wgt * tmid;
        T *= (1.0f - va);
    }
    float bg = 1.0f - op;
    c0 += bg; c1 += bg; c2 += bg;
    out[3 * r + 0] = c0;
    out[3 * r + 1] = c1;
    out[3 * r + 2] = c2;
    out[3 * NR + r] = op;
    out[4 * NR + r] = dp;
}

extern "C" void kernel_launch(void* const* d_in, const int* in_sizes, int n_in,
                              void* d_out, int out_size, void* d_ws, size_t ws_size,
                              hipStream_t stream) {
    const float* rays_o   = (const float*)d_in[0];
    const float* viewdirs = (const float*)d_in[1];
    const float* t_starts = (const float*)d_in[2];
    const float* t_ends   = (const float*)d_in[3];
    const float* W1  = (const float*)d_in[4];
    const float* b1  = (const float*)d_in[5];
    const float* W2  = (const float*)d_in[6];
    const float* b2  = (const float*)d_in[7];
    const float* Wd  = (const float*)d_in[8];
    const float* bd  = (const float*)d_in[9];
    const float* Wf  = (const float*)d_in[10];
    const float* bf_ = (const float*)d_in[11];
    const float* Wr1 = (const float*)d_in[12];
    const float* br1 = (const float*)d_in[13];
    const float* Wr2 = (const float*)d_in[14];
    const float* br2 = (const float*)d_in[15];
    const int* ridx  = (const int*)d_in[16];
    float* out = (float*)d_out;

    char* ws = (char*)d_ws;
    uint2* rgba  = (uint2*)ws;
    float* tmarr = (float*)(ws + (size_t)NS * 8);
    int* start   = (int*)(ws + (size_t)NS * 12);
    int* end     = start + NR;
    uint4* wfrag = (uint4*)(ws + (size_t)NS * 12 + (size_t)NR * 8);
    uint4* dtab  = (uint4*)(ws + (size_t)NS * 12 + (size_t)NR * 8 + 40 * 64 * 16);

    setup_kernel<<<522, 256, 0, stream>>>(viewdirs, dtab, start, end,
                                          W1, W2, Wf, Wr1, Wd, Wr2, wfrag);
    find_bounds<<<NS / 256, 256, 0, stream>>>(ridx, start, end);
    fused_mlp<<<NS / 256, 256, 0, stream>>>(
        rays_o, viewdirs, t_starts, t_ends,
        b1, b2, bd, bf_, br1, br2, ridx, wfrag, dtab, rgba, tmarr);
    render_kernel<<<NR / 256, 256, 0, stream>>>(rgba, tmarr, start, end, out);
}

// Round 11
// 141.228 us; speedup vs baseline: 1.3233x; 1.0242x over previous
//
#include <hip/hip_runtime.h>
#include <math.h>

#define NR 65536
#define NS 2097152

typedef __attribute__((ext_vector_type(4))) float f32x4;
typedef __attribute__((ext_vector_type(2))) float f32x2;
typedef __attribute__((ext_vector_type(8))) short short8;

#define RSTRIDE 36             // dwords per sample row (32 act + dtv + sig + 2 pad)
#define GSTRIDE (16 * 36 + 4)  // 580 dwords per 16-sample group

// ---------------- workspace layout ----------------
// [0, NS*8)                 : uint2 rgba (bf16 r,g | b,alpha) per sample
// [NS*8, +NS*4)             : float tmid[NS]
// [NS*12, +NR*8)            : int start[NR], end[NR]
// [NS*12+NR*8, +40KB)       : uint4 wfrag[40*64]  (A-fragments, bf16, W^T)
// [.. +40KB, +4MB)          : uint4 dtab[NR*4]    (per-ray dir-enc, bf16)

// Native bf16 conversion (RNE fptrunc) — compiler lowers to HW cvt.
__device__ __forceinline__ uint packbf(float a, float b) {
    __bf16 lo = (__bf16)a, hi = (__bf16)b;
    ushort ul = __builtin_bit_cast(ushort, lo);
    ushort uh = __builtin_bit_cast(ushort, hi);
    return (uint)ul | ((uint)uh << 16);
}
__device__ __forceinline__ float bflo(uint u) { return __builtin_bit_cast(float, u << 16); }

// Merged setup: blocks 0-255 direnc, 256-511 init_bounds, 512-521 build_frags.
__global__ void setup_kernel(const float* __restrict__ viewdirs,
                             uint4* __restrict__ dtab,
                             int* __restrict__ start, int* __restrict__ end,
                             const float* __restrict__ W1, const float* __restrict__ W2,
                             const float* __restrict__ Wf, const float* __restrict__ Wr1,
                             const float* __restrict__ Wd, const float* __restrict__ Wr2,
                             uint4* __restrict__ wfrag) {
    int b = blockIdx.x, tid = threadIdx.x;
    if (b < 256) {
        // ---- per-ray dir posenc -> 4 uint4 per ray ----
        int r = b * 256 + tid;
        float dx = viewdirs[3 * r + 0], dy = viewdirs[3 * r + 1], dz = viewdirs[3 * r + 2];
        float de[32];
        de[0] = dx; de[1] = dy; de[2] = dz;
        float sx = __sinf(dx), cx = __cosf(dx);
        float sy = __sinf(dy), cy = __cosf(dy);
        float sz = __sinf(dz), cz = __cosf(dz);
        #pragma unroll
        for (int l = 0; l < 4; ++l) {
            de[3 + 6 * l + 0] = sx; de[3 + 6 * l + 1] = sy; de[3 + 6 * l + 2] = sz;
            de[3 + 6 * l + 3] = cx; de[3 + 6 * l + 4] = cy; de[3 + 6 * l + 5] = cz;
            float nsx = 2.0f * sx * cx, nsy = 2.0f * sy * cy, nsz = 2.0f * sz * cz;
            cx = fmaf(-2.0f * sx, sx, 1.0f);
            cy = fmaf(-2.0f * sy, sy, 1.0f);
            cz = fmaf(-2.0f * sz, sz, 1.0f);
            sx = nsx; sy = nsy; sz = nsz;
        }
        #pragma unroll
        for (int k = 27; k < 32; ++k) de[k] = 0.0f;
        #pragma unroll
        for (int c = 0; c < 4; ++c) {
            uint4 q = make_uint4(packbf(de[8 * c + 0], de[8 * c + 1]),
                                 packbf(de[8 * c + 2], de[8 * c + 3]),
                                 packbf(de[8 * c + 4], de[8 * c + 5]),
                                 packbf(de[8 * c + 6], de[8 * c + 7]));
            dtab[(size_t)r * 4 + c] = q;
        }
    } else if (b < 512) {
        int r = (b - 256) * 256 + tid;
        start[r] = 0; end[r] = 0;
    } else {
        // ---- build A-fragments (W^T), order: L1 0-7, L2 8-15, Wf 16-23,
        //      Wr1 24-35, Wd 36-37, Wr2 38-39 ----
        int t = (b - 512) * 256 + tid;
        if (t >= 40 * 64) return;
        int f = t >> 6, lane = t & 63;
        int c = lane & 15;
        uint q[4];
        if (f < 36) {
            const float* W; int kmax, fl;
            if (f < 8)       { W = W1;  kmax = 63; fl = f; }
            else if (f < 16) { W = W2;  kmax = 64; fl = f - 8; }
            else if (f < 24) { W = Wf;  kmax = 64; fl = f - 16; }
            else             { W = Wr1; kmax = 91; fl = f - 24; }
            int ks = fl >> 2, ft = fl & 3;
            int n = ft * 16 + c;
            int kb = ks * 32 + ((lane >> 4) * 8);
            #pragma unroll
            for (int j = 0; j < 4; ++j) {
                int k0 = kb + 2 * j, k1 = k0 + 1;
                float v0 = (k0 < kmax) ? W[k0 * 64 + n] : 0.0f;
                float v1 = (k1 < kmax) ? W[k1 * 64 + n] : 0.0f;
                q[j] = packbf(v0, v1);
            }
        } else if (f < 38) {          // sigma tile: A[m][k] = (m==0) ? Wd[k] : 0
            int kb = (f - 36) * 32 + ((lane >> 4) * 8);
            #pragma unroll
            for (int j = 0; j < 4; ++j) {
                float v0 = (c == 0) ? Wd[kb + 2 * j] : 0.0f;
                float v1 = (c == 0) ? Wd[kb + 2 * j + 1] : 0.0f;
                q[j] = packbf(v0, v1);
            }
        } else {                      // rgb tile: A[m][k] = (m<3) ? Wr2[k*3+m] : 0
            int kb = (f - 38) * 32 + ((lane >> 4) * 8);
            #pragma unroll
            for (int j = 0; j < 4; ++j) {
                float v0 = (c < 3) ? Wr2[(kb + 2 * j) * 3 + c] : 0.0f;
                float v1 = (c < 3) ? Wr2[(kb + 2 * j + 1) * 3 + c] : 0.0f;
                q[j] = packbf(v0, v1);
            }
        }
        wfrag[(size_t)f * 64 + lane] = make_uint4(q[0], q[1], q[2], q[3]);
    }
}

// LDS layout (sample-major, unswizzled; RSTRIDE=36 => 9 chunks/row, 9 odd =>
// b128 slot map (9s+g) mod 8 is perfectly 2-lane-balanced per quarter-wave):
//   group st base = (w*4+st)*GSTRIDE; sample row = + s*RSTRIDE.
//   Dwords 0..31 = activations (64 feats bf16), 32 = dtv, 33 = sigma.

template <int KS, bool RELU, bool SIGMA, bool DIRB>
__device__ __forceinline__ void dense_layer(uint* S, const uint4* __restrict__ wfrag,
                                            int fb, const float* __restrict__ bias,
                                            float bd0, uint rbase, uint wbA, uint wbB,
                                            int lane, const uint4 (&dirB)[4]) {
    const int g = lane >> 4;
    uint4 wf[KS * 4];
    #pragma unroll
    for (int i = 0; i < KS * 4; ++i) wf[i] = wfrag[(size_t)(fb + i) * 64 + lane];
    uint4 wsg[2];
    if constexpr (SIGMA) {
        wsg[0] = wfrag[36 * 64 + lane];
        wsg[1] = wfrag[37 * 64 + lane];
    }
    float4 bfr[4];
    #pragma unroll
    for (int ft = 0; ft < 4; ++ft)
        bfr[ft] = *(const float4*)(bias + 16 * ft + 4 * g);

    #pragma unroll
    for (int st = 0; st < 4; ++st) {
        const uint stoff = (uint)st * (uint)GSTRIDE;
        uint4 B[KS];
        #pragma unroll
        for (int ks = 0; ks < KS; ++ks) {
            if (DIRB && ks == KS - 1) B[ks] = dirB[st];
            else B[ks] = *(const uint4*)&S[rbase + stoff + 16u * (uint)ks];  // ds_read_b128
        }
        f32x4 acc[4];
        #pragma unroll
        for (int ft = 0; ft < 4; ++ft)
            acc[ft] = (f32x4){bfr[ft].x, bfr[ft].y, bfr[ft].z, bfr[ft].w};
        f32x4 sacc;
        if constexpr (SIGMA) sacc = (f32x4){(g == 0) ? bd0 : 0.0f, 0.0f, 0.0f, 0.0f};
        #pragma unroll
        for (int ks = 0; ks < KS; ++ks) {
            short8 bv = __builtin_bit_cast(short8, B[ks]);
            #pragma unroll
            for (int ft = 0; ft < 4; ++ft)
                acc[ft] = __builtin_amdgcn_mfma_f32_16x16x32_bf16(
                    __builtin_bit_cast(short8, wf[ks * 4 + ft]), bv, acc[ft], 0, 0, 0);
            if constexpr (SIGMA)
                sacc = __builtin_amdgcn_mfma_f32_16x16x32_bf16(
                    __builtin_bit_cast(short8, wsg[ks]), bv, sacc, 0, 0, 0);
        }
        // D layout: col = lane&15 = sample, row = 4g + reg = out-feature.
        #pragma unroll
        for (int ft = 0; ft < 4; ++ft) {
            f32x2 lo = {acc[ft][0], acc[ft][1]};
            f32x2 hi = {acc[ft][2], acc[ft][3]};
            if constexpr (RELU) {
                lo = __builtin_elementwise_max(lo, (f32x2){0.0f, 0.0f});  // v_pk_max_f32
                hi = __builtin_elementwise_max(hi, (f32x2){0.0f, 0.0f});
            }
            uint2 v = make_uint2(packbf(lo.x, lo.y), packbf(hi.x, hi.y));
            uint base = (ft & 1) ? wbB : wbA;
            *(uint2*)&S[base + stoff + 16u * (uint)(ft >> 1)] = v;      // ds_write_b64
        }
        if constexpr (SIGMA) {
            if (g == 0) S[rbase + stoff + 33u] = __builtin_bit_cast(uint, sacc[0]);
        }
    }
}

__global__ __launch_bounds__(256, 4) void fused_mlp(
    const float* __restrict__ rays_o, const float* __restrict__ viewdirs,
    const float* __restrict__ t_starts, const float* __restrict__ t_ends,
    const float* __restrict__ b1, const float* __restrict__ b2,
    const float* __restrict__ bd, const float* __restrict__ bf_,
    const float* __restrict__ br1, const float* __restrict__ br2,
    const int* __restrict__ ridx, const uint4* __restrict__ wfrag,
    const uint4* __restrict__ dtab, uint2* __restrict__ rgba,
    float* __restrict__ tmarr, int* __restrict__ start, int* __restrict__ end)
{
    __shared__ uint S[16 * GSTRIDE];   // 9280 dwords = 37120 B -> 4 blocks/CU

    const int tid = threadIdx.x;
    const int w = tid >> 6, lane = tid & 63;
    const int g = lane >> 4, s = lane & 15;
    const uint wgb = (uint)(w * 4) * (uint)GSTRIDE;
    const uint rowcol = wgb + (uint)s * (uint)RSTRIDE;
    const int sb0 = blockIdx.x * 256 + w * 64;

    // ---- ridx for this thread's 4 B-samples (st, s) + own sample (st=g) ----
    int ridx4[4];
    #pragma unroll
    for (int st = 0; st < 4; ++st) ridx4[st] = ridx[sb0 + st * 16 + s];
    uint4 dirB[4];
    #pragma unroll
    for (int st = 0; st < 4; ++st) dirB[st] = dtab[(size_t)ridx4[st] * 4 + g];

    const int si = sb0 + g * 16 + s;
    const int rr = ridx4[g];

    // ---- segment bounds for own sample (folded find_bounds) ----
    {
        int r_prev = ridx[(si == 0) ? 0 : si - 1];
        int r_next = ridx[(si == NS - 1) ? NS - 1 : si + 1];
        if (si == 0 || r_prev != rr) start[rr] = si;
        if (si == NS - 1 || r_next != rr) end[rr] = si + 1;
    }

    float ts = t_starts[si], te = t_ends[si];
    float tm = 0.5f * (ts + te), dtv = te - ts;
    float dx = viewdirs[3 * rr + 0], dy = viewdirs[3 * rr + 1], dz = viewdirs[3 * rr + 2];
    float px = rays_o[3 * rr + 0] + dx * tm;
    float py = rays_o[3 * rr + 1] + dy * tm;
    float pz = rays_o[3 * rr + 2] + dz * tm;
    tmarr[si] = tm;                                   // render reads this (coalesced)

    // Per-thread base registers:
    const uint ownrow = wgb + (uint)g * (uint)GSTRIDE + (uint)s * (uint)RSTRIDE;
    const uint rbase = rowcol + 4u * (uint)g;
    const uint wbA = rowcol + 2u * (uint)g;
    const uint wbB = wbA + 8u;

    // ---- posenc(pts,10), x/y packed (v_pk_* f32), z scalar ----
    {
        float enc[64];
        enc[0] = px; enc[1] = py; enc[2] = pz;
        f32x2 sxy = {__sinf(px), __sinf(py)};
        f32x2 cxy = {__cosf(px), __cosf(py)};
        float sz = __sinf(pz), cz = __cosf(pz);
        #pragma unroll
        for (int l = 0; l < 10; ++l) {
            enc[3 + 6 * l + 0] = sxy.x; enc[3 + 6 * l + 1] = sxy.y; enc[3 + 6 * l + 2] = sz;
            enc[3 + 6 * l + 3] = cxy.x; enc[3 + 6 * l + 4] = cxy.y; enc[3 + 6 * l + 5] = cz;
            f32x2 nsxy = 2.0f * sxy * cxy;
            cxy = 1.0f - 2.0f * sxy * sxy;
            float nsz = 2.0f * sz * cz;
            cz = fmaf(-2.0f * sz, sz, 1.0f);
            sxy = nsxy; sz = nsz;
        }
        enc[63] = 0.0f;
        #pragma unroll
        for (int ch = 0; ch < 8; ++ch) {
            uint4 q = make_uint4(packbf(enc[8 * ch + 0], enc[8 * ch + 1]),
                                 packbf(enc[8 * ch + 2], enc[8 * ch + 3]),
                                 packbf(enc[8 * ch + 4], enc[8 * ch + 5]),
                                 packbf(enc[8 * ch + 6], enc[8 * ch + 7]));
            *(uint4*)&S[ownrow + 4u * (uint)ch] = q;                    // ds_write_b128
        }
    }
    S[ownrow + 32] = __builtin_bit_cast(uint, dtv);                     // dtv in row pad

    float bd0 = bd[0];
    uint4 dummy[4];

    dense_layer<2, true,  false, false>(S, wfrag,  0, b1,  0.0f, rbase, wbA, wbB, lane, dummy);
    dense_layer<2, true,  false, false>(S, wfrag,  8, b2,  0.0f, rbase, wbA, wbB, lane, dummy);
    dense_layer<2, false, true,  false>(S, wfrag, 16, bf_, bd0,  rbase, wbA, wbB, lane, dummy);
    dense_layer<3, true,  false, true >(S, wfrag, 24, br1, 0.0f, rbase, wbA, wbB, lane, dirB);

    // ---- rgb tile + epilogue ----
    {
        uint4 wr0 = wfrag[38 * 64 + lane], wr1f = wfrag[39 * 64 + lane];
        float c0 = br2[0], c1 = br2[1], c2 = br2[2];
        #pragma unroll
        for (int st = 0; st < 4; ++st) {
            const uint stoff = (uint)st * (uint)GSTRIDE;
            uint4 B0 = *(const uint4*)&S[rbase + stoff];           // feat chunks g
            uint4 B1 = *(const uint4*)&S[rbase + stoff + 16u];     // feat chunks 4+g
            f32x4 acc = (g == 0) ? (f32x4){c0, c1, c2, 0.0f}
                                 : (f32x4){0.0f, 0.0f, 0.0f, 0.0f};
            acc = __builtin_amdgcn_mfma_f32_16x16x32_bf16(
                __builtin_bit_cast(short8, wr0), __builtin_bit_cast(short8, B0), acc, 0, 0, 0);
            acc = __builtin_amdgcn_mfma_f32_16x16x32_bf16(
                __builtin_bit_cast(short8, wr1f), __builtin_bit_cast(short8, B1), acc, 0, 0, 0);
            if (lane < 16) {
                // g==0 here, so rbase == rowcol: pad dwords of row (st, lane).
                uint2 meta = *(const uint2*)&S[rbase + stoff + 32u];   // {dtv, sigma}
                float dte = __builtin_bit_cast(float, meta.x);
                float sg = fmaxf(__builtin_bit_cast(float, meta.y), 0.0f);
                float alpha = 1.0f - __expf(-sg * dte);
                float r0 = 1.0f / (1.0f + __expf(-acc[0]));
                float r1 = 1.0f / (1.0f + __expf(-acc[1]));
                float r2 = 1.0f / (1.0f + __expf(-acc[2]));
                uint2 o;
                o.x = packbf(r0, r1);
                o.y = packbf(r2, alpha);
                rgba[sb0 + st * 16 + lane] = o;
            }
        }
    }
}

__global__ void render_kernel(const uint2* __restrict__ rgba,
                              const float* __restrict__ tmarr,
                              const int* __restrict__ start,
                              const int* __restrict__ end,
                              float* __restrict__ out)
{
    int r = blockIdx.x * blockDim.x + threadIdx.x;
    if (r >= NR) return;
    int sb = start[r], e = end[r];
    float T = 1.0f, c0 = 0.0f, c1 = 0.0f, c2 = 0.0f, op = 0.0f, dp = 0.0f;
    for (int i = sb; i < e; ++i) {
        uint2 q = rgba[i];
        float tmid = tmarr[i];
        float vr = bflo(q.x & 0xffffu), vg = bflo(q.x >> 16);
        float vb = bflo(q.y & 0xffffu), va = bflo(q.y >> 16);
        float wgt = T * va;
        c0 += wgt * vr; c1 += wgt * vg; c2 += wgt * vb;
        op += wgt; dp += wgt * tmid;
        T *= (1.0f - va);
    }
    float bg = 1.0f - op;
    c0 += bg; c1 += bg; c2 += bg;
    out[3 * r + 0] = c0;
    out[3 * r + 1] = c1;
    out[3 * r + 2] = c2;
    out[3 * NR + r] = op;
    out[4 * NR + r] = dp;
}

extern "C" void kernel_launch(void* const* d_in, const int* in_sizes, int n_in,
                              void* d_out, int out_size, void* d_ws, size_t ws_size,
                              hipStream_t stream) {
    const float* rays_o   = (const float*)d_in[0];
    const float* viewdirs = (const float*)d_in[1];
    const float* t_starts = (const float*)d_in[2];
    const float* t_ends   = (const float*)d_in[3];
    const float* W1  = (const float*)d_in[4];
    const float* b1  = (const float*)d_in[5];
    const float* W2  = (const float*)d_in[6];
    const float* b2  = (const float*)d_in[7];
    const float* Wd  = (const float*)d_in[8];
    const float* bd  = (const float*)d_in[9];
    const float* Wf  = (const float*)d_in[10];
    const float* bf_ = (const float*)d_in[11];
    const float* Wr1 = (const float*)d_in[12];
    const float* br1 = (const float*)d_in[13];
    const float* Wr2 = (const float*)d_in[14];
    const float* br2 = (const float*)d_in[15];
    const int* ridx  = (const int*)d_in[16];
    float* out = (float*)d_out;

    char* ws = (char*)d_ws;
    uint2* rgba  = (uint2*)ws;
    float* tmarr = (float*)(ws + (size_t)NS * 8);
    int* start   = (int*)(ws + (size_t)NS * 12);
    int* end     = start + NR;
    uint4* wfrag = (uint4*)(ws + (size_t)NS * 12 + (size_t)NR * 8);
    uint4* dtab  = (uint4*)(ws + (size_t)NS * 12 + (size_t)NR * 8 + 40 * 64 * 16);

    setup_kernel<<<522, 256, 0, stream>>>(viewdirs, dtab, start, end,
                                          W1, W2, Wf, Wr1, Wd, Wr2, wfrag);
    fused_mlp<<<NS / 256, 256, 0, stream>>>(
        rays_o, viewdirs, t_starts, t_ends,
        b1, b2, bd, bf_, br1, br2, ridx, wfrag, dtab, rgba, tmarr, start, end);
    render_kernel<<<NR / 256, 256, 0, stream>>>(rgba, tmarr, start, end, out);
}